// Round 1
// baseline (87.081 us; speedup 1.0000x reference)
//
#include <hip/hip_runtime.h>

// Tropical (max-plus) linear layer:
//   out[b, j] = max_k (x[b,k] + w[j,k]) + bias[j]   if any product > -1e38
//             = -1e38                                otherwise
// x: [4096, 256] f32, w: [256, 256] f32, bias: [256] f32, out: [4096, 256] f32

#define TZERO -1e38f

constexpr int Bdim = 4096;
constexpr int K    = 256;
constexpr int N    = 256;
constexpr int BM   = 64;   // rows per block
constexpr int BN   = 32;   // cols per block
constexpr int BK   = 32;   // k-chunk
constexpr int XLD  = BM + 4;  // 68 floats -> 272 B row stride (16B aligned)
constexpr int WLD  = BN + 4;  // 36 floats -> 144 B row stride (16B aligned)
constexpr int NT   = 128;  // threads per block: (BM/4) * (BN/4) = 16*8

__global__ __launch_bounds__(NT)
void tropical_kernel(const float* __restrict__ x, const float* __restrict__ w,
                     const float* __restrict__ bias, float* __restrict__ out)
{
    __shared__ float xs[BK][XLD];   // transposed: xs[k][row]
    __shared__ float ws[BK][WLD];   // transposed: ws[k][col]

    const int t    = threadIdx.x;
    const int tx   = t & 15;        // 0..15 -> 4-row group
    const int ty   = t >> 4;        // 0..7  -> 4-col group
    const int row0 = blockIdx.x * BM;
    const int col0 = blockIdx.y * BN;

    float acc[4][4];
#pragma unroll
    for (int i = 0; i < 4; ++i)
#pragma unroll
        for (int j = 0; j < 4; ++j)
            acc[i][j] = -__builtin_inff();

    for (int kc = 0; kc < K; kc += BK) {
        // ---- stage x tile (BM rows x BK k), transposed into xs[k][row] ----
#pragma unroll
        for (int i = 0; i < 4; ++i) {
            const int f  = t + i * NT;   // 0..511
            const int r  = f >> 3;       // 0..63
            const int k4 = f & 7;        // 0..7 (float4 index within chunk)
            const float4 v = *reinterpret_cast<const float4*>(
                &x[(size_t)(row0 + r) * K + kc + k4 * 4]);
            xs[k4 * 4 + 0][r] = v.x;
            xs[k4 * 4 + 1][r] = v.y;
            xs[k4 * 4 + 2][r] = v.z;
            xs[k4 * 4 + 3][r] = v.w;
        }
        // ---- stage w tile (BN cols x BK k), transposed into ws[k][col] ----
#pragma unroll
        for (int i = 0; i < 2; ++i) {
            const int f  = t + i * NT;   // 0..255
            const int c  = f >> 3;       // 0..31
            const int k4 = f & 7;
            const float4 v = *reinterpret_cast<const float4*>(
                &w[(size_t)(col0 + c) * K + kc + k4 * 4]);
            ws[k4 * 4 + 0][c] = v.x;
            ws[k4 * 4 + 1][c] = v.y;
            ws[k4 * 4 + 2][c] = v.z;
            ws[k4 * 4 + 3][c] = v.w;
        }
        __syncthreads();

        // ---- compute: pair two k-steps so fmax chains fold to v_max3_f32 ----
#pragma unroll
        for (int k = 0; k < BK; k += 2) {
            float xa[4], xb[4], wa[4], wb[4];
            *reinterpret_cast<float4*>(xa) =
                *reinterpret_cast<const float4*>(&xs[k][tx * 4]);
            *reinterpret_cast<float4*>(xb) =
                *reinterpret_cast<const float4*>(&xs[k + 1][tx * 4]);
            *reinterpret_cast<float4*>(wa) =
                *reinterpret_cast<const float4*>(&ws[k][ty * 4]);
            *reinterpret_cast<float4*>(wb) =
                *reinterpret_cast<const float4*>(&ws[k + 1][ty * 4]);
#pragma unroll
            for (int i = 0; i < 4; ++i)
#pragma unroll
                for (int j = 0; j < 4; ++j) {
                    const float t0 = xa[i] + wa[j];
                    const float t1 = xb[i] + wb[j];
                    acc[i][j] = fmaxf(fmaxf(acc[i][j], t0), t1);
                }
        }
        __syncthreads();
    }

    // ---- epilogue: bias only when a valid (> -1e38) product exists ----
    float bj[4];
    *reinterpret_cast<float4*>(bj) =
        *reinterpret_cast<const float4*>(&bias[col0 + ty * 4]);
#pragma unroll
    for (int i = 0; i < 4; ++i) {
        float4 o;
        o.x = (acc[i][0] > TZERO) ? acc[i][0] + bj[0] : TZERO;
        o.y = (acc[i][1] > TZERO) ? acc[i][1] + bj[1] : TZERO;
        o.z = (acc[i][2] > TZERO) ? acc[i][2] + bj[2] : TZERO;
        o.w = (acc[i][3] > TZERO) ? acc[i][3] + bj[3] : TZERO;
        *reinterpret_cast<float4*>(
            &out[(size_t)(row0 + tx * 4 + i) * N + col0 + ty * 4]) = o;
    }
}

extern "C" void kernel_launch(void* const* d_in, const int* in_sizes, int n_in,
                              void* d_out, int out_size, void* d_ws, size_t ws_size,
                              hipStream_t stream) {
    const float* x  = (const float*)d_in[0];
    const float* w  = (const float*)d_in[1];
    const float* b  = (const float*)d_in[2];
    float* out      = (float*)d_out;

    dim3 grid(Bdim / BM, N / BN);  // (64, 8) = 512 blocks
    tropical_kernel<<<grid, NT, 0, stream>>>(x, w, b, out);
}

// Round 2
// 76.899 us; speedup vs baseline: 1.1324x; 1.1324x over previous
//
#include <hip/hip_runtime.h>

// Tropical (max-plus) linear layer:
//   out[b, j] = max_k (x[b,k] + w[j,k]) + bias[j]   if any product > -1e38
//             = -1e38                                otherwise
// x: [4096, 256] f32, w: [256, 256] f32, bias: [256] f32, out: [4096, 256] f32
//
// Structure: barrier-free K-loop.
//  - block = 4 waves, 256 threads; block tile = 32 rows x 64 cols
//  - wave tile = 8 rows x 64 cols, 1 col per lane (acc[8] in VGPRs)
//  - w tile (64 cols x 256 k) staged to LDS ONCE as wQ[k4][j] float4 (64 KB),
//    k-loop reads are lane-contiguous ds_read_b128 (conflict-free)
//  - x rows are wave-uniform -> scalar s_load path, no LDS, no barriers in loop

#define TZERO -1e38f

constexpr int K    = 256;
constexpr int N    = 256;
constexpr int RPW  = 8;            // rows per wave
constexpr int WAVES = 4;
constexpr int BM   = RPW * WAVES;  // 32 rows per block
constexpr int BN   = 64;           // cols per block (= lanes)
constexpr int NT   = 64 * WAVES;   // 256 threads

__global__ __launch_bounds__(NT, 2)
void tropical_kernel(const float* __restrict__ x, const float* __restrict__ w,
                     const float* __restrict__ bias, float* __restrict__ out)
{
    __shared__ float4 wQ[64][64];   // [k4][j] -> w[col0+j][4*k4 .. 4*k4+3], 64 KB

    const int t    = threadIdx.x;
    const int row0 = blockIdx.x * BM;
    const int col0 = blockIdx.y * BN;

    // ---- stage w tile once: gather (strided global, one-time, L2-resident)
    //      -> contiguous LDS writes (canonical lane-contiguous b128, no conflicts)
#pragma unroll
    for (int i = 0; i < (64 * 64) / NT; ++i) {
        const int flat = t + i * NT;     // 0..4095
        const int j    = flat & 63;      // col within tile (fast across lanes)
        const int k4   = flat >> 6;      // k-group
        wQ[k4][j] = *reinterpret_cast<const float4*>(
            w + (size_t)(col0 + j) * K + k4 * 4);
    }
    __syncthreads();   // the ONLY barrier

    const int lane = t & 63;
    const int wave = __builtin_amdgcn_readfirstlane(t >> 6);
    const float* xw = x + (size_t)(row0 + wave * RPW) * K;  // wave-uniform

    float acc[RPW];
#pragma unroll
    for (int r = 0; r < RPW; ++r) acc[r] = -__builtin_inff();

#pragma unroll 4
    for (int k4 = 0; k4 < K / 4; ++k4) {
        const float4 wv = wQ[k4][lane];          // ds_read_b128, conflict-free
#pragma unroll
        for (int r = 0; r < RPW; ++r) {
            // uniform address -> scalar loads (SGPR), free of VALU/LDS
            const float4 xv = *reinterpret_cast<const float4*>(xw + r * K + k4 * 4);
            const float t0 = xv.x + wv.x;
            const float t1 = xv.y + wv.y;
            const float t2 = xv.z + wv.z;
            const float t3 = xv.w + wv.w;
            // folds to two v_max3_f32
            float m = fmaxf(fmaxf(acc[r], t0), t1);
            m       = fmaxf(fmaxf(m, t2), t3);
            acc[r] = m;
        }
    }

    // ---- epilogue: 1 col per lane, coalesced dword stores
    const float bj = bias[col0 + lane];
    float* orow = out + (size_t)(row0 + wave * RPW) * N + col0 + lane;
#pragma unroll
    for (int r = 0; r < RPW; ++r) {
        const float v = acc[r];
        orow[(size_t)r * N] = (v > TZERO) ? v + bj : TZERO;
    }
}

extern "C" void kernel_launch(void* const* d_in, const int* in_sizes, int n_in,
                              void* d_out, int out_size, void* d_ws, size_t ws_size,
                              hipStream_t stream) {
    const float* x  = (const float*)d_in[0];
    const float* w  = (const float*)d_in[1];
    const float* b  = (const float*)d_in[2];
    float* out      = (float*)d_out;

    dim3 grid(4096 / BM, N / BN);   // (128, 4) = 512 blocks, 4 waves each
    tropical_kernel<<<grid, NT, 0, stream>>>(x, w, b, out);
}

// Round 3
// 72.966 us; speedup vs baseline: 1.1935x; 1.0539x over previous
//
#include <hip/hip_runtime.h>

// Tropical (max-plus) linear layer:
//   out[b, j] = max_k (x[b,k] + w[j,k]) + bias[j]   if any product > -1e38
//             = -1e38                                otherwise
// x: [4096, 256] f32, w: [256, 256] f32, bias: [256] f32, out: [4096, 256] f32
//
// R3 structure: occupancy-first.
//  - RPW=4 outputs/lane -> 4096 waves -> 16 waves/CU (4/SIMD), vs 8/CU in R2
//  - w staged in k-chunks of 64 via 2x16KB LDS ping-pong (32 KB/block)
//    -> 4 blocks/CU; 1 barrier per chunk, overlapped across blocks
//  - k-loop per k4: 1 conflict-free ds_read_b128 (w) + 4 wave-uniform x float4
//    (scalar-load path) + 24 VALU (16 v_add + 8 v_max3)

#define TZERO -1e38f

constexpr int K     = 256;
constexpr int N     = 256;
constexpr int RPW   = 4;             // rows per wave
constexpr int WAVES = 4;
constexpr int BM    = RPW * WAVES;   // 16 rows per block
constexpr int BN    = 64;            // cols per block (= lanes)
constexpr int NT    = 64 * WAVES;    // 256 threads
constexpr int BK    = 64;            // k-chunk
constexpr int NC    = K / BK;        // 4 chunks
constexpr int K4C   = BK / 4;        // 16 float4-groups per chunk

__global__ __launch_bounds__(NT, 4)
void tropical_kernel(const float* __restrict__ x, const float* __restrict__ w,
                     const float* __restrict__ bias, float* __restrict__ out)
{
    __shared__ float4 wQ[2][K4C][BN];   // ping-pong: [buf][k4][col], 2 x 16 KB

    const int t    = threadIdx.x;
    const int lane = t & 63;
    const int wave = __builtin_amdgcn_readfirstlane(t >> 6);
    const int row0 = blockIdx.x * BM + wave * RPW;
    const int col0 = blockIdx.y * BN;

    // staging assignment: thread t covers col (t&63), k4-quarter (t>>6)
    const int scol = t & 63;
    const int sq   = t >> 6;   // 0..3
    const float* wsrc = w + (size_t)(col0 + scol) * K + sq * 16;

    // ---- prologue: stage chunk 0 into buffer 0
#pragma unroll
    for (int i = 0; i < 4; ++i)
        wQ[0][sq * 4 + i][scol] =
            *reinterpret_cast<const float4*>(wsrc + i * 4);
    __syncthreads();

    const float* xw = x + (size_t)row0 * K;   // wave-uniform

    float acc[RPW];
#pragma unroll
    for (int r = 0; r < RPW; ++r) acc[r] = -__builtin_inff();

    for (int c = 0; c < NC; ++c) {
        // ---- prefetch next chunk into the other buffer (no barrier needed:
        //      previous barrier guaranteed everyone is done reading it)
        if (c + 1 < NC) {
            const float* ws = wsrc + (c + 1) * BK;
#pragma unroll
            for (int i = 0; i < 4; ++i)
                wQ[(c + 1) & 1][sq * 4 + i][scol] =
                    *reinterpret_cast<const float4*>(ws + i * 4);
        }

        // ---- compute current chunk
        const float* xc = xw + c * BK;
#pragma unroll 8
        for (int k4 = 0; k4 < K4C; ++k4) {
            const float4 wv = wQ[c & 1][k4][lane];   // ds_read_b128, no conflict
#pragma unroll
            for (int r = 0; r < RPW; ++r) {
                // wave-uniform address -> scalar load path
                const float4 xv =
                    *reinterpret_cast<const float4*>(xc + r * K + k4 * 4);
                const float t0 = xv.x + wv.x;
                const float t1 = xv.y + wv.y;
                const float t2 = xv.z + wv.z;
                const float t3 = xv.w + wv.w;
                float m = fmaxf(fmaxf(acc[r], t0), t1);   // v_max3_f32
                m       = fmaxf(fmaxf(m, t2), t3);        // v_max3_f32
                acc[r] = m;
            }
        }
        __syncthreads();
    }

    // ---- epilogue: 1 col per lane, coalesced dword stores
    const float bj = bias[col0 + lane];
    float* orow = out + (size_t)row0 * N + col0 + lane;
#pragma unroll
    for (int r = 0; r < RPW; ++r) {
        const float v = acc[r];
        orow[(size_t)r * N] = (v > TZERO) ? v + bj : TZERO;
    }
}

extern "C" void kernel_launch(void* const* d_in, const int* in_sizes, int n_in,
                              void* d_out, int out_size, void* d_ws, size_t ws_size,
                              hipStream_t stream) {
    const float* x  = (const float*)d_in[0];
    const float* w  = (const float*)d_in[1];
    const float* b  = (const float*)d_in[2];
    float* out      = (float*)d_out;

    dim3 grid(4096 / BM, N / BN);   // (256, 4) = 1024 blocks, 4 waves each
    tropical_kernel<<<grid, NT, 0, stream>>>(x, w, b, out);
}